// Round 8
// baseline (4767.897 us; speedup 1.0000x reference)
//
#include <hip/hip_runtime.h>
#include <hip/hip_fp16.h>

// 2-layer LSTM B=256 T=512 I=32 H=256.
// 8 groups x 32 batches x 16 wgs (384 thr, 6 waves).
// Waves: 0,1=L0 (batch halves); 2,3=L1-A (Wih1*h0 + merge + h1 store);
// 4,5=L1-B (Whh1*h1 partial -> LDS xch). All 4 gates per lane.
// Transport: fp16 h with 1-bit lap tag in LSB through MALL (sc0 sc1) 2-slot
// rings; consumers spin-load their OWN A-frags directly (no LDS staging).
// Writers poll reader load-ACK bytes (undrained) before clobbering a slot.
// One raw s_barrier per phase (xch handoff, parity double-buffered).
// L1-B has 2-phase slack; only the L0 chain is latency-critical (1 MALL leg).

#define TT 512
#define HH 256

typedef _Float16 f16x8 __attribute__((ext_vector_type(8)));
typedef float    f32x4 __attribute__((ext_vector_type(4)));
typedef unsigned u32x4 __attribute__((ext_vector_type(4)));

__device__ __forceinline__ f16x8 cvt8(const float* p) {
  const float4 a = *(const float4*)p;
  const float4 b = *(const float4*)(p + 4);
  f16x8 r;
  r[0]=(_Float16)a.x; r[1]=(_Float16)a.y; r[2]=(_Float16)a.z; r[3]=(_Float16)a.w;
  r[4]=(_Float16)b.x; r[5]=(_Float16)b.y; r[6]=(_Float16)b.z; r[7]=(_Float16)b.w;
  return r;
}
__device__ __forceinline__ float sigm(float x){ return 1.f/(1.f + __expf(-x)); }
__device__ __forceinline__ float tanh_(float x){ return 1.f - 2.f/(1.f + __expf(2.f*x)); }

// ---- MALL-coherent (L2-bypass) primitives ----
__device__ __forceinline__ u32x4 ld16_sv(unsigned voff, const void* base) {
  u32x4 r;
  asm volatile("global_load_dwordx4 %0, %1, %2 sc0 sc1"
               : "=v"(r) : "v"(voff), "s"(base) : "memory");
  return r;
}
__device__ __forceinline__ void st2_sv(unsigned voff, unsigned v, void* base) {
  asm volatile("global_store_short %0, %1, %2 sc0 sc1"
               :: "v"(voff), "v"(v), "s"(base) : "memory");
}
__device__ __forceinline__ void st1(void* p, unsigned v) {
  asm volatile("global_store_byte %0, %1, off sc0 sc1"
               :: "v"(p), "v"(v) : "memory");
}
__device__ __forceinline__ unsigned ld1_nw(const void* p) {   // no embedded wait
  unsigned r;
  asm volatile("global_load_ubyte %0, %1, off sc0 sc1"
               : "=v"(r) : "v"(p) : "memory");
  return r;
}
__device__ __forceinline__ unsigned ld1_w(const void* p) {    // self-waiting
  unsigned r;
  asm volatile("global_load_ubyte %0, %1, off sc0 sc1\n\ts_waitcnt vmcnt(0)"
               : "=v"(r) : "v"(p) : "memory");
  return r;
}
__device__ __forceinline__ void wvm0() {
  asm volatile("s_waitcnt vmcnt(0)" ::: "memory");
  __builtin_amdgcn_sched_barrier(0);
}
__device__ __forceinline__ void barrier_lds() {   // no vmcnt drain
  __builtin_amdgcn_sched_barrier(0);
  asm volatile("s_waitcnt lgkmcnt(0)" ::: "memory");
  __builtin_amdgcn_s_barrier();
  __builtin_amdgcn_sched_barrier(0);
}
// lap tag of step t (valid t >= -2): 0,0,1,1,0,0,...
__device__ __forceinline__ unsigned tg(int t){ return ((unsigned)(t + 4) >> 1) & 1u; }

__global__ void init_ws(uint4* p, int n) {
  int i = blockIdx.x * blockDim.x + threadIdx.x;
  if (i >= n) return;
  p[i] = (i < 32768) ? make_uint4(0x00010001u,0x00010001u,0x00010001u,0x00010001u)
                     : make_uint4(0u,0u,0u,0u);   // flag bytes = 0
}

__global__ __launch_bounds__(384) void lstm_v8(
    const float* __restrict__ M,
    const float* __restrict__ Wih0, const float* __restrict__ Whh0,
    const float* __restrict__ bih0, const float* __restrict__ bhh0,
    const float* __restrict__ Wih1, const float* __restrict__ Whh1,
    const float* __restrict__ bih1, const float* __restrict__ bhh1,
    float* __restrict__ out, char* __restrict__ ws)
{
  __shared__ __align__(16) f32x4 xch[2][8][64];   // [parity][hf*4+q][lane]

  const int tid  = threadIdx.x, lane = tid & 63, wv = tid >> 6;  // 0..5
  const int g    = blockIdx.x & 7;      // group (XCD heuristic)
  const int w    = blockIdx.x >> 3;     // unit tile 0..15
  const int hf   = wv & 1;              // batch half
  const int role = wv >> 1;             // 0:L0  1:L1-A  2:L1-B
  const int col16 = lane & 15, ko8 = (lane >> 4) << 3;
  const int unit = w * 16 + col16;

  // rings: h0 [2 slots][g][32 b][256 u] fp16; h1 likewise at +256KB
  #define H0R(slot) (ws + (((g << 1) | (slot)) << 14))
  #define H1R(slot) (ws + 262144 + (((g << 1) | (slot)) << 14))
  unsigned char* flg = (unsigned char*)(ws + 524288) + (g << 7); // [0:63]=ha,[64:95]=b1

  // ---- register-resident weights: 4 gates x 16 units ----
  f16x8 W0[4][8], WI[4];
  float bias[4] = {0.f, 0.f, 0.f, 0.f};
  if (role == 0) {
    #pragma unroll
    for (int q = 0; q < 4; ++q) {
      const int row = q * HH + unit;
      #pragma unroll
      for (int kt = 0; kt < 8; ++kt)
        W0[q][kt] = cvt8(Whh0 + (size_t)row * HH + kt * 32 + ko8);
      WI[q]   = cvt8(Wih0 + (size_t)row * 32 + ko8);
      bias[q] = bih0[row] + bhh0[row];
    }
  } else if (role == 1) {
    #pragma unroll
    for (int q = 0; q < 4; ++q) {
      const int row = q * HH + unit;
      #pragma unroll
      for (int kt = 0; kt < 8; ++kt)
        W0[q][kt] = cvt8(Wih1 + (size_t)row * HH + kt * 32 + ko8);
      bias[q] = bih1[row] + bhh1[row];
    }
  } else {
    #pragma unroll
    for (int q = 0; q < 4; ++q) {
      const int row = q * HH + unit;
      #pragma unroll
      for (int kt = 0; kt < 8; ++kt)
        W0[q][kt] = cvt8(Whh1 + (size_t)row * HH + kt * 32 + ko8);
    }
  }

  // A-frag read offset (row = batch), store offsets (row = batch, col = unit)
  const unsigned hoff = (((unsigned)(hf * 16 + col16)) << 9) | ((unsigned)(lane >> 4) << 4);
  unsigned soff[4];
  #pragma unroll
  for (int r = 0; r < 4; ++r)
    soff[r] = (((unsigned)(hf * 16 + ((lane >> 4) << 2) + r)) << 9) | ((unsigned)unit << 1);

  // M prefetch (L0): A rows = batches
  const float* mp = M + (size_t)(g * 32 + hf * 16 + col16) * TT * 32 + ko8;
  float4 m0 = {0,0,0,0}, m1 = {0,0,0,0};
  if (role == 0) { m0 = *(const float4*)mp; m1 = *(const float4*)(mp + 4); }

  float cst[4] = {0.f, 0.f, 0.f, 0.f};

  for (int p = 0; p <= TT; ++p) {
    u32x4 hbuf[8];
    // ================= head: spin-load own A-frags + ack publish =================
    if (role == 0) {
      if (p >= 1 && p < TT) {
        const char* s = H0R((p - 1) & 1);
        const unsigned pat = tg(p - 1) * 0x00010001u;
        const unsigned char tgt = (unsigned char)p;
        for (;;) {
          #pragma unroll
          for (int k = 0; k < 8; ++k) hbuf[k] = ld16_sv(hoff + k * 64, s);
          unsigned fb = ld1_nw(flg + lane);          // all 64 ha bytes
          wvm0();
          unsigned bad = 0;
          #pragma unroll
          for (int k = 0; k < 8; ++k) {
            const u32x4 d = (hbuf[k] ^ pat) & 0x00010001u;
            bad |= d[0] | d[1] | d[2] | d[3];
          }
          int ok = (bad == 0) &&
                   ((int)(signed char)((unsigned char)fb - tgt) >= 0);
          if (__all(ok)) break;
          __builtin_amdgcn_s_sleep(1);
        }
      }
      if (p < TT && lane == 0)
        st1(flg + (w * 4 + hf * 2 + 0), (unsigned)((p + 1) & 0xFF));   // ha(L0)
    } else if (role == 1) {
      if (p >= 1) {
        const char* s = H0R((p - 1) & 1);
        const unsigned pat = tg(p - 1) * 0x00010001u;
        for (;;) {
          #pragma unroll
          for (int k = 0; k < 8; ++k) hbuf[k] = ld16_sv(hoff + k * 64, s);
          wvm0();
          unsigned bad = 0;
          #pragma unroll
          for (int k = 0; k < 8; ++k) {
            const u32x4 d = (hbuf[k] ^ pat) & 0x00010001u;
            bad |= d[0] | d[1] | d[2] | d[3];
          }
          if (__all(bad == 0)) break;
          __builtin_amdgcn_s_sleep(1);
        }
      }
      if (lane == 0)
        st1(flg + (w * 4 + hf * 2 + 1), (unsigned)((p + 1) & 0xFF));   // ha(L1A)
    } else {
      if (p >= 2) {
        const char* s = H1R(p & 1);                  // (p-2)&1 == p&1
        const unsigned pat = tg(p - 2) * 0x00010001u;
        for (;;) {
          #pragma unroll
          for (int k = 0; k < 8; ++k) hbuf[k] = ld16_sv(hoff + k * 64, s);
          wvm0();
          unsigned bad = 0;
          #pragma unroll
          for (int k = 0; k < 8; ++k) {
            const u32x4 d = (hbuf[k] ^ pat) & 0x00010001u;
            bad |= d[0] | d[1] | d[2] | d[3];
          }
          if (__all(bad == 0)) break;
          __builtin_amdgcn_s_sleep(1);
        }
      }
      if (lane == 0)
        st1(flg + 64 + (w * 2 + hf), (unsigned)((p + 1) & 0xFF));      // b1
    }

    // ================= compute =================
    f32x4 acc[4];
    if (role == 0 && p < TT) {
      f16x8 am;
      am[0]=(_Float16)m0.x; am[1]=(_Float16)m0.y; am[2]=(_Float16)m0.z; am[3]=(_Float16)m0.w;
      am[4]=(_Float16)m1.x; am[5]=(_Float16)m1.y; am[6]=(_Float16)m1.z; am[7]=(_Float16)m1.w;
      #pragma unroll
      for (int q = 0; q < 4; ++q) {
        acc[q] = (f32x4){bias[q], bias[q], bias[q], bias[q]};
        acc[q] = __builtin_amdgcn_mfma_f32_16x16x32_f16(am, WI[q], acc[q], 0, 0, 0);
      }
      if (p >= 1) {
        #pragma unroll
        for (int kt = 0; kt < 8; ++kt) {
          const f16x8 A = __builtin_bit_cast(f16x8, hbuf[kt]);
          #pragma unroll
          for (int q = 0; q < 4; ++q)
            acc[q] = __builtin_amdgcn_mfma_f32_16x16x32_f16(A, W0[q][kt], acc[q], 0, 0, 0);
        }
      }
      if (p + 1 < TT) {                   // prefetch M[t+1]
        m0 = *(const float4*)(mp + (p + 1) * 32);
        m1 = *(const float4*)(mp + (p + 1) * 32 + 4);
      }
    } else if (role == 1 && p >= 1) {
      #pragma unroll
      for (int q = 0; q < 4; ++q)
        acc[q] = (f32x4){bias[q], bias[q], bias[q], bias[q]};
      #pragma unroll
      for (int kt = 0; kt < 8; ++kt) {
        const f16x8 A = __builtin_bit_cast(f16x8, hbuf[kt]);
        #pragma unroll
        for (int q = 0; q < 4; ++q)
          acc[q] = __builtin_amdgcn_mfma_f32_16x16x32_f16(A, W0[q][kt], acc[q], 0, 0, 0);
      }
    } else if (role == 2 && p >= 2) {
      #pragma unroll
      for (int q = 0; q < 4; ++q) acc[q] = (f32x4){0.f, 0.f, 0.f, 0.f};
      #pragma unroll
      for (int kt = 0; kt < 8; ++kt) {
        const f16x8 A = __builtin_bit_cast(f16x8, hbuf[kt]);
        #pragma unroll
        for (int q = 0; q < 4; ++q)
          acc[q] = __builtin_amdgcn_mfma_f32_16x16x32_f16(A, W0[q][kt], acc[q], 0, 0, 0);
      }
      #pragma unroll
      for (int q = 0; q < 4; ++q) xch[p & 1][hf * 4 + q][lane] = acc[q];
    }

    barrier_lds();                        // xch handoff (parity dbuf)

    // ================= tail: elementwise + tagged stores =================
    if (role == 0 && p < TT) {
      char* d = H0R(p & 1);
      const unsigned wt = tg(p);
      #pragma unroll
      for (int r = 0; r < 4; ++r) {
        const float iv = sigm(acc[0][r]), fv = sigm(acc[1][r]);
        const float gv = tanh_(acc[2][r]), ov = sigm(acc[3][r]);
        cst[r] = fv * cst[r] + iv * gv;
        const float h = ov * tanh_(cst[r]);
        unsigned short hb = __builtin_bit_cast(unsigned short, (_Float16)h);
        hb = (unsigned short)((hb & 0xFFFEu) | wt);
        st2_sv(soff[r], (unsigned)hb, d);   // fire-and-forget
      }
    } else if (role == 1 && p >= 1) {
      if (p >= 2) {
        #pragma unroll
        for (int q = 0; q < 4; ++q) acc[q] = acc[q] + xch[p & 1][hf * 4 + q][lane];
      }
      if (p < TT) {
        // clobber-guard: h1[p-3] readers (L1-B@p-1) done loading?
        const unsigned char tgt = (unsigned char)p;
        for (;;) {
          unsigned fb = 0;
          if (lane < 32) fb = ld1_w(flg + 64 + lane);
          int ok = (lane < 32)
                 ? ((int)(signed char)((unsigned char)fb - tgt) >= 0) : 1;
          if (__all(ok)) break;
          __builtin_amdgcn_s_sleep(1);
        }
        char* d = H1R((p - 1) & 1);
        const unsigned wt = tg(p - 1);
        #pragma unroll
        for (int r = 0; r < 4; ++r) {
          const float iv = sigm(acc[0][r]), fv = sigm(acc[1][r]);
          const float gv = tanh_(acc[2][r]), ov = sigm(acc[3][r]);
          cst[r] = fv * cst[r] + iv * gv;
          const float h = ov * tanh_(cst[r]);
          unsigned short hb = __builtin_bit_cast(unsigned short, (_Float16)h);
          hb = (unsigned short)((hb & 0xFFFEu) | wt);
          st2_sv(soff[r], (unsigned)hb, d);
        }
      } else {
        #pragma unroll
        for (int r = 0; r < 4; ++r) {
          const float iv = sigm(acc[0][r]), fv = sigm(acc[1][r]);
          const float gv = tanh_(acc[2][r]), ov = sigm(acc[3][r]);
          cst[r] = fv * cst[r] + iv * gv;
          const float h = ov * tanh_(cst[r]);
          const int b = hf * 16 + ((lane >> 4) << 2) + r;
          out[(size_t)(g * 32 + b) * HH + unit] = h;   // final h1[T-1], fp32
        }
      }
    }
  }
  #undef H0R
  #undef H1R
}

extern "C" void kernel_launch(void* const* d_in, const int* in_sizes, int n_in,
                              void* d_out, int out_size, void* d_ws, size_t ws_size,
                              hipStream_t stream) {
  (void)in_sizes; (void)n_in; (void)out_size;
  if (ws_size < 525312) return;   // 512KB rings + 1KB flags

  const float* M    = (const float*)d_in[0];
  const float* Wih0 = (const float*)d_in[1];
  const float* Whh0 = (const float*)d_in[2];
  const float* bih0 = (const float*)d_in[3];
  const float* bhh0 = (const float*)d_in[4];
  const float* Wih1 = (const float*)d_in[5];
  const float* Whh1 = (const float*)d_in[6];
  const float* bih1 = (const float*)d_in[7];
  const float* bhh1 = (const float*)d_in[8];

  const int n16 = 32832;           // 32768 ring uint4s + 64 flag uint4s
  init_ws<<<(n16 + 255) / 256, 256, 0, stream>>>((uint4*)d_ws, n16);
  lstm_v8<<<128, 384, 0, stream>>>(M, Wih0, Whh0, bih0, bhh0,
                                   Wih1, Whh1, bih1, bhh1,
                                   (float*)d_out, (char*)d_ws);
}

// Round 9
// 1580.289 us; speedup vs baseline: 3.0171x; 3.0171x over previous
//
#include <hip/hip_runtime.h>
#include <hip/hip_fp16.h>

// 2-layer LSTM B=256 T=512 I=32 H=256.
// 8 groups x 32 batches x 16 wgs (512 thr, 8 waves).
// Waves: 0,1=L0; 2,3=L1-A (Wih1*h0, merge, h1 store); 4,5=L1-B (Whh1*h1);
// 6,7=stage helpers. All 4 gates per lane (in-register elementwise).
// Transport: fp16 h with 1-bit lap tag in LSB via MALL (sc0 sc1) 2-slot rings.
// ZERO flags/acks/drains: 2-slot ring + lap tag is structurally safe (a wg can
// only overwrite slot s for step t after all wgs passed stage t-1, which needs
// this wg's t-1 stores). Phase: [stage h0 spin] bar [L0 mfma+store | L1A mfma |
// L1B mid-phase h1 spin+mfma->xch] bar [L1A merge+store]. L0 leg = 1 MALL RTT.

#define TT 512
#define HH 256

typedef _Float16 f16x8 __attribute__((ext_vector_type(8)));
typedef float    f32x4 __attribute__((ext_vector_type(4)));
typedef unsigned u32x4 __attribute__((ext_vector_type(4)));

__device__ __forceinline__ f16x8 cvt8(const float* p) {
  const float4 a = *(const float4*)p;
  const float4 b = *(const float4*)(p + 4);
  f16x8 r;
  r[0]=(_Float16)a.x; r[1]=(_Float16)a.y; r[2]=(_Float16)a.z; r[3]=(_Float16)a.w;
  r[4]=(_Float16)b.x; r[5]=(_Float16)b.y; r[6]=(_Float16)b.z; r[7]=(_Float16)b.w;
  return r;
}
__device__ __forceinline__ float sigm(float x){ return 1.f/(1.f + __expf(-x)); }
__device__ __forceinline__ float tanh_(float x){ return 1.f - 2.f/(1.f + __expf(2.f*x)); }

// ---- MALL-coherent (L2-bypass) primitives ----
__device__ __forceinline__ u32x4 ld16_sv(unsigned voff, const void* base) {
  u32x4 r;
  asm volatile("global_load_dwordx4 %0, %1, %2 sc0 sc1"
               : "=v"(r) : "v"(voff), "s"(base) : "memory");
  return r;
}
__device__ __forceinline__ void st2_sv(unsigned voff, unsigned v, void* base) {
  asm volatile("global_store_short %0, %1, %2 sc0 sc1"
               :: "v"(voff), "v"(v), "s"(base) : "memory");
}
__device__ __forceinline__ void wvm0() {
  asm volatile("s_waitcnt vmcnt(0)" ::: "memory");
  __builtin_amdgcn_sched_barrier(0);
}
__device__ __forceinline__ void barrier_lds() {   // lgkm drain only, no vmcnt
  __builtin_amdgcn_sched_barrier(0);
  asm volatile("s_waitcnt lgkmcnt(0)" ::: "memory");
  __builtin_amdgcn_s_barrier();
  __builtin_amdgcn_sched_barrier(0);
}
// lap tag of step t (valid t >= -2): 1,1,0,0,1,1,0,0,... period 4
__device__ __forceinline__ unsigned tg(int t){ return ((unsigned)(t + 4) >> 1) & 1u; }

__global__ void init_ws(uint4* p, int n) {
  int i = blockIdx.x * blockDim.x + threadIdx.x;
  if (i < n) p[i] = make_uint4(0x00010001u,0x00010001u,0x00010001u,0x00010001u);
}

__global__ __launch_bounds__(512) void lstm_v9(
    const float* __restrict__ M,
    const float* __restrict__ Wih0, const float* __restrict__ Whh0,
    const float* __restrict__ bih0, const float* __restrict__ bhh0,
    const float* __restrict__ Wih1, const float* __restrict__ Whh1,
    const float* __restrict__ bih1, const float* __restrict__ bhh1,
    float* __restrict__ out, char* __restrict__ ws)
{
  __shared__ __align__(16) char  ldsA[16384];     // h0[p-1] A-frags [hf][kt][lane]
  __shared__ __align__(16) f32x4 xch[8][64];      // L1-B -> L1-A partials

  const int tid  = threadIdx.x, lane = tid & 63, wv = tid >> 6;
  const int g    = blockIdx.x & 7;      // group (XCD heuristic, r2-proven)
  const int w    = blockIdx.x >> 3;     // unit tile 0..15
  const int hf   = wv & 1;              // batch half
  const int role = wv >> 1;             // 0:L0 1:L1A 2:L1B 3:stager
  const int col16 = lane & 15, ko8 = (lane >> 4) << 3;
  const int unit = w * 16 + col16;

  // rings: h0 [2 slots][g][32 b][256 u] fp16 (16KB/slot); h1 at +256KB
  #define H0R(slot) (ws + (((g << 1) | (slot)) << 14))
  #define H1R(slot) (ws + 262144 + (((g << 1) | (slot)) << 14))

  // ---- register-resident weights: 4 gates x 16 units ----
  f16x8 W0[4][8], WI[4];
  float bias[4] = {0.f, 0.f, 0.f, 0.f};
  if (role == 0) {
    #pragma unroll
    for (int q = 0; q < 4; ++q) {
      const int row = q * HH + unit;
      #pragma unroll
      for (int kt = 0; kt < 8; ++kt)
        W0[q][kt] = cvt8(Whh0 + (size_t)row * HH + kt * 32 + ko8);
      WI[q]   = cvt8(Wih0 + (size_t)row * 32 + ko8);
      bias[q] = bih0[row] + bhh0[row];
    }
  } else if (role == 1) {
    #pragma unroll
    for (int q = 0; q < 4; ++q) {
      const int row = q * HH + unit;
      #pragma unroll
      for (int kt = 0; kt < 8; ++kt)
        W0[q][kt] = cvt8(Wih1 + (size_t)row * HH + kt * 32 + ko8);
      bias[q] = bih1[row] + bhh1[row];
    }
  } else if (role == 2) {
    #pragma unroll
    for (int q = 0; q < 4; ++q) {
      const int row = q * HH + unit;
      #pragma unroll
      for (int kt = 0; kt < 8; ++kt)
        W0[q][kt] = cvt8(Whh1 + (size_t)row * HH + kt * 32 + ko8);
    }
  }

  // staging decode: thread (skt, sl) -> h0 frag (kt=skt, lane=sl), both halves
  const int sl  = tid & 63;
  const int skt = (tid >> 6) & 7;
  const unsigned moff0 = (unsigned)((sl & 15) * 512 + skt * 64 + (sl >> 4) * 16);
  const unsigned moff1 = moff0 + 16 * 512;
  const unsigned lo    = (unsigned)(skt * 1024 + sl * 16);

  // L1-B direct h1 A-frag offsets (row = batch)
  const unsigned hoff = (((unsigned)(hf * 16 + col16)) << 9) | ((unsigned)(lane >> 4) << 4);
  // store offsets (row = batch, col = unit)
  unsigned soff[4];
  #pragma unroll
  for (int r = 0; r < 4; ++r)
    soff[r] = (((unsigned)(hf * 16 + ((lane >> 4) << 2) + r)) << 9) | ((unsigned)unit << 1);

  // M prefetch (L0 only)
  const float* mp = M + (size_t)(g * 32 + hf * 16 + col16) * TT * 32 + ko8;
  float4 m0 = {0,0,0,0}, m1 = {0,0,0,0};
  if (role == 0) { m0 = *(const float4*)mp; m1 = *(const float4*)(mp + 4); }

  float cst[4] = {0.f, 0.f, 0.f, 0.f};

  for (int p = 0; p <= TT; ++p) {
    // ========== stage h0[p-1] into LDS (all 512 threads), tag-spun ==========
    if (p >= 1) {
      const char* s = H0R((p - 1) & 1);
      const unsigned pat = tg(p - 1) * 0x00010001u;
      u32x4 v0 = ld16_sv(moff0, s), v1 = ld16_sv(moff1, s);
      wvm0();
      for (;;) {
        const u32x4 d = ((v0 ^ pat) | (v1 ^ pat)) & 0x00010001u;
        if (__all((d[0] | d[1] | d[2] | d[3]) == 0)) break;
        v0 = ld16_sv(moff0, s); v1 = ld16_sv(moff1, s);
        wvm0();
      }
      *(u32x4*)(ldsA + lo)        = v0;
      *(u32x4*)(ldsA + 8192 + lo) = v1;
    }
    barrier_lds();

    // ========== compute ==========
    f32x4 acc[4];
    if (role == 0 && p < TT) {
      f16x8 am;
      am[0]=(_Float16)m0.x; am[1]=(_Float16)m0.y; am[2]=(_Float16)m0.z; am[3]=(_Float16)m0.w;
      am[4]=(_Float16)m1.x; am[5]=(_Float16)m1.y; am[6]=(_Float16)m1.z; am[7]=(_Float16)m1.w;
      #pragma unroll
      for (int q = 0; q < 4; ++q) {
        acc[q] = (f32x4){bias[q], bias[q], bias[q], bias[q]};
        acc[q] = __builtin_amdgcn_mfma_f32_16x16x32_f16(am, WI[q], acc[q], 0, 0, 0);
      }
      if (p >= 1) {
        #pragma unroll
        for (int kt = 0; kt < 8; ++kt) {
          const f16x8 A = *(const f16x8*)(ldsA + hf * 8192 + kt * 1024 + lane * 16);
          #pragma unroll
          for (int q = 0; q < 4; ++q)
            acc[q] = __builtin_amdgcn_mfma_f32_16x16x32_f16(A, W0[q][kt], acc[q], 0, 0, 0);
        }
      }
      // elementwise + tagged h0[p] store EARLY (before 2nd barrier)
      char* d = H0R(p & 1);
      const unsigned wt = tg(p);
      #pragma unroll
      for (int r = 0; r < 4; ++r) {
        const float iv = sigm(acc[0][r]), fv = sigm(acc[1][r]);
        const float gv = tanh_(acc[2][r]), ov = sigm(acc[3][r]);
        cst[r] = fv * cst[r] + iv * gv;
        const float h = ov * tanh_(cst[r]);
        unsigned short hb = __builtin_bit_cast(unsigned short, (_Float16)h);
        hb = (unsigned short)((hb & 0xFFFEu) | wt);
        st2_sv(soff[r], (unsigned)hb, d);     // fire-and-forget
      }
      if (p + 1 < TT) {                        // prefetch M[p+1]
        m0 = *(const float4*)(mp + (p + 1) * 32);
        m1 = *(const float4*)(mp + (p + 1) * 32 + 4);
      }
    } else if (role == 1 && p >= 1) {
      #pragma unroll
      for (int q = 0; q < 4; ++q)
        acc[q] = (f32x4){bias[q], bias[q], bias[q], bias[q]};
      #pragma unroll
      for (int kt = 0; kt < 8; ++kt) {
        const f16x8 A = *(const f16x8*)(ldsA + hf * 8192 + kt * 1024 + lane * 16);
        #pragma unroll
        for (int q = 0; q < 4; ++q)
          acc[q] = __builtin_amdgcn_mfma_f32_16x16x32_f16(A, W0[q][kt], acc[q], 0, 0, 0);
      }
    } else if (role == 2 && p >= 2) {
      // mid-phase spin on own h1[p-2] frags (stored at tail of phase p-1)
      const char* s = H1R(p & 1);               // (p-2)&1 == p&1
      const unsigned pat = tg(p - 2) * 0x00010001u;
      u32x4 hb[8];
      #pragma unroll
      for (int k = 0; k < 8; ++k) hb[k] = ld16_sv(hoff + k * 64, s);
      wvm0();
      for (;;) {
        unsigned bad = 0;
        #pragma unroll
        for (int k = 0; k < 8; ++k) {
          const u32x4 d = (hb[k] ^ pat) & 0x00010001u;
          bad |= d[0] | d[1] | d[2] | d[3];
        }
        if (__all(bad == 0)) break;
        #pragma unroll
        for (int k = 0; k < 8; ++k) hb[k] = ld16_sv(hoff + k * 64, s);
        wvm0();
      }
      #pragma unroll
      for (int q = 0; q < 4; ++q) acc[q] = (f32x4){0.f, 0.f, 0.f, 0.f};
      #pragma unroll
      for (int kt = 0; kt < 8; ++kt) {
        const f16x8 A = __builtin_bit_cast(f16x8, hb[kt]);
        #pragma unroll
        for (int q = 0; q < 4; ++q)
          acc[q] = __builtin_amdgcn_mfma_f32_16x16x32_f16(A, W0[q][kt], acc[q], 0, 0, 0);
      }
      #pragma unroll
      for (int q = 0; q < 4; ++q) xch[hf * 4 + q][lane] = acc[q];
    }
    barrier_lds();

    // ========== tail: L1-A merge + elementwise + h1[p-1] store ==========
    if (role == 1 && p >= 1) {
      if (p >= 2) {
        #pragma unroll
        for (int q = 0; q < 4; ++q) acc[q] = acc[q] + xch[hf * 4 + q][lane];
      }
      if (p < TT) {
        char* d = H1R((p - 1) & 1);
        const unsigned wt = tg(p - 1);
        #pragma unroll
        for (int r = 0; r < 4; ++r) {
          const float iv = sigm(acc[0][r]), fv = sigm(acc[1][r]);
          const float gv = tanh_(acc[2][r]), ov = sigm(acc[3][r]);
          cst[r] = fv * cst[r] + iv * gv;
          const float h = ov * tanh_(cst[r]);
          unsigned short hb = __builtin_bit_cast(unsigned short, (_Float16)h);
          hb = (unsigned short)((hb & 0xFFFEu) | wt);
          st2_sv(soff[r], (unsigned)hb, d);   // fire-and-forget
        }
      } else {
        #pragma unroll
        for (int r = 0; r < 4; ++r) {
          const float iv = sigm(acc[0][r]), fv = sigm(acc[1][r]);
          const float gv = tanh_(acc[2][r]), ov = sigm(acc[3][r]);
          cst[r] = fv * cst[r] + iv * gv;
          const float h = ov * tanh_(cst[r]);
          const int b = hf * 16 + ((lane >> 4) << 2) + r;
          out[(size_t)(g * 32 + b) * HH + unit] = h;   // final h1[T-1], fp32
        }
      }
    }
  }
  #undef H0R
  #undef H1R
}

extern "C" void kernel_launch(void* const* d_in, const int* in_sizes, int n_in,
                              void* d_out, int out_size, void* d_ws, size_t ws_size,
                              hipStream_t stream) {
  (void)in_sizes; (void)n_in; (void)out_size;
  if (ws_size < 524288) return;   // 512KB rings

  const float* M    = (const float*)d_in[0];
  const float* Wih0 = (const float*)d_in[1];
  const float* Whh0 = (const float*)d_in[2];
  const float* bih0 = (const float*)d_in[3];
  const float* bhh0 = (const float*)d_in[4];
  const float* Wih1 = (const float*)d_in[5];
  const float* Whh1 = (const float*)d_in[6];
  const float* bih1 = (const float*)d_in[7];
  const float* bhh1 = (const float*)d_in[8];

  init_ws<<<128, 256, 0, stream>>>((uint4*)d_ws, 32768);
  lstm_v9<<<128, 512, 0, stream>>>(M, Wih0, Whh0, bih0, bhh0,
                                   Wih1, Whh1, bih1, bhh1,
                                   (float*)d_out, (char*)d_ws);
}